// Round 1
// baseline (684.804 us; speedup 1.0000x reference)
//
#include <hip/hip_runtime.h>
#include <hip/hip_bf16.h>

// BiasedAxialAttention on MI355X (gfx950), round 0: bf16-MFMA pipeline.
// Needs ws_size >= ~287 MB.

#define LQ 384
#define DE 128
#define DBI 64
#define NH 4
#define DH 48
#define NPOS (LQ*LQ)     // 147456
#define KQK (LQ*DH)      // 18432
#define LDSS 72          // padded LDS row stride (bf16 elems) for BK=64 tiles

typedef __attribute__((ext_vector_type(8))) short short8;
typedef __attribute__((ext_vector_type(4))) float f32x4;
typedef unsigned short u16;
typedef unsigned int u32;

__device__ __forceinline__ float b2f(u16 u) {
  union { u32 i; float f; } v; v.i = ((u32)u) << 16; return v.f;
}
__device__ __forceinline__ u16 f2b(float f) {
  __hip_bfloat16 h = __float2bfloat16(f);
  return __builtin_bit_cast(unsigned short, h);
}
__device__ __forceinline__ float wred_sum(float v) {
  #pragma unroll
  for (int o = 32; o; o >>= 1) v += __shfl_down(v, o);
  return __shfl(v, 0);
}

// ---------------- generic NT-GEMM mainloop: block = 256 thr (4 waves),
// tile M=128 x N=16*NF, BK=64. A rows are M (K-major), B rows are N (K-major).
template<int NF>
__device__ __forceinline__ void gemm_loop(
    const u16* __restrict__ Ag, long lda,
    const u16* __restrict__ Bg, long ldb,
    int kTiles, u16* sA, u16* sB, f32x4 (&acc)[2][NF])
{
  const int t = threadIdx.x;
  const int w = t >> 6, lane = t & 63, quad = lane >> 4, l16 = lane & 15;
  for (int kt = 0; kt < kTiles; ++kt) {
    const u16* As = Ag + (long)kt * 64;
    #pragma unroll
    for (int r = 0; r < 4; ++r) {
      int id = t + r * 256;
      int row = id >> 3, c8 = (id & 7) * 8;
      *(uint4*)(sA + row * LDSS + c8) = *(const uint4*)(As + (long)row * lda + c8);
    }
    const u16* Bs = Bg + (long)kt * 64;
    #pragma unroll
    for (int r = 0; r < (NF * 128 + 255) / 256; ++r) {
      int id = t + r * 256;
      if (id < NF * 128) {
        int row = id >> 3, c8 = (id & 7) * 8;
        *(uint4*)(sB + row * LDSS + c8) = *(const uint4*)(Bs + (long)row * ldb + c8);
      }
    }
    __syncthreads();
    #pragma unroll
    for (int kk = 0; kk < 64; kk += 32) {
      short8 a0 = *(const short8*)(sA + (w * 32 + l16) * LDSS + kk + quad * 8);
      short8 a1 = *(const short8*)(sA + (w * 32 + 16 + l16) * LDSS + kk + quad * 8);
      #pragma unroll
      for (int f = 0; f < NF; ++f) {
        short8 bf = *(const short8*)(sB + (f * 16 + l16) * LDSS + kk + quad * 8);
        acc[0][f] = __builtin_amdgcn_mfma_f32_16x16x32_bf16(a0, bf, acc[0][f], 0, 0, 0);
        acc[1][f] = __builtin_amdgcn_mfma_f32_16x16x32_bf16(a1, bf, acc[1][f], 0, 0, 0);
      }
    }
    __syncthreads();
  }
}

// variant with A = A1 .* A2 (elementwise bf16 product fused into LDS staging), NF=4
__device__ __forceinline__ void gemm_loop_mul(
    const u16* __restrict__ A1, const u16* __restrict__ A2, long lda,
    const u16* __restrict__ Bg, long ldb,
    int kTiles, u16* sA, u16* sB, f32x4 (&acc)[2][4])
{
  const int t = threadIdx.x;
  const int w = t >> 6, lane = t & 63, quad = lane >> 4, l16 = lane & 15;
  for (int kt = 0; kt < kTiles; ++kt) {
    #pragma unroll
    for (int r = 0; r < 4; ++r) {
      int id = t + r * 256;
      int row = id >> 3, c8 = (id & 7) * 8;
      long off = (long)row * lda + kt * 64 + c8;
      union { u16 s[8]; uint4 v; } ua, ub, ur;
      ua.v = *(const uint4*)(A1 + off);
      ub.v = *(const uint4*)(A2 + off);
      #pragma unroll
      for (int q2 = 0; q2 < 8; ++q2) ur.s[q2] = f2b(b2f(ua.s[q2]) * b2f(ub.s[q2]));
      *(uint4*)(sA + row * LDSS + c8) = ur.v;
    }
    #pragma unroll
    for (int r = 0; r < 2; ++r) {
      int id = t + r * 256;
      int row = id >> 3, c8 = (id & 7) * 8;
      *(uint4*)(sB + row * LDSS + c8) = *(const uint4*)(Bg + (long)row * ldb + kt * 64 + c8);
    }
    __syncthreads();
    #pragma unroll
    for (int kk = 0; kk < 64; kk += 32) {
      short8 a0 = *(const short8*)(sA + (w * 32 + l16) * LDSS + kk + quad * 8);
      short8 a1 = *(const short8*)(sA + (w * 32 + 16 + l16) * LDSS + kk + quad * 8);
      #pragma unroll
      for (int f = 0; f < 4; ++f) {
        short8 bf = *(const short8*)(sB + (f * 16 + l16) * LDSS + kk + quad * 8);
        acc[0][f] = __builtin_amdgcn_mfma_f32_16x16x32_bf16(a0, bf, acc[0][f], 0, 0, 0);
        acc[1][f] = __builtin_amdgcn_mfma_f32_16x16x32_bf16(a1, bf, acc[1][f], 0, 0, 0);
      }
    }
    __syncthreads();
  }
}

// ---------------- kernel 0: weight transposes -> bf16 (K-major rows for NT GEMM)
__global__ __launch_bounds__(256) void k_prep_w(
    const float* __restrict__ Wq, const float* __restrict__ Wk,
    const float* __restrict__ Wv, const float* __restrict__ Wg,
    const float* __restrict__ Wo, u16* __restrict__ WT, u16* __restrict__ WoT)
{
  int idx = blockIdx.x * 256 + threadIdx.x;
  if (idx < 768 * 128) {
    int col = idx >> 7, c = idx & 127;
    int which = col / 192, wi = col % 192;
    const float* W = (which == 0) ? Wq : (which == 1) ? Wk : (which == 2) ? Wv : Wg;
    WT[(long)col * 128 + c] = f2b(W[(long)c * 192 + wi]);
  }
  if (idx < 128 * 192) {
    int c = idx / 192, col = idx % 192;
    WoT[(long)c * 192 + col] = f2b(Wo[(long)col * 128 + c]);
  }
}

// ---------------- kernel 1: LN of transposed edge -> e_ln bf16 [p = n*384+i][128]
__global__ __launch_bounds__(256) void k_ln_e(
    const float* __restrict__ edge, const float* __restrict__ g,
    const float* __restrict__ b, u16* __restrict__ e_ln)
{
  int w = threadIdx.x >> 6, lane = threadIdx.x & 63;
  long p = (long)blockIdx.x * 4 + w;
  int n = (int)(p / LQ), i2 = (int)(p % LQ);
  const float* src = edge + ((long)i2 * LQ + n) * DE;   // transposed read
  float2 x = *(const float2*)(src + lane * 2);
  float mu = wred_sum(x.x + x.y) * (1.f / 128.f);
  float ms = wred_sum(x.x * x.x + x.y * x.y) * (1.f / 128.f);
  float r = rsqrtf(ms - mu * mu + 1e-5f);
  int c = lane * 2;
  u16 y0 = f2b((x.x - mu) * r * g[c] + b[c]);
  u16 y1 = f2b((x.y - mu) * r * g[c + 1] + b[c + 1]);
  *(u32*)(e_ln + p * DE + c) = (u32)y0 | ((u32)y1 << 16);
}

// ---------------- kernel 2: LN(bias^T) @ Wb -> logits init (= b_h)  [h][i][j]
__global__ __launch_bounds__(256) void k_bias(
    const float* __restrict__ bias, const float* __restrict__ g,
    const float* __restrict__ b, const float* __restrict__ Wb,
    float* __restrict__ logits)
{
  int w = threadIdx.x >> 6, lane = threadIdx.x & 63;
  long q = (long)blockIdx.x * 4 + w;
  int i = (int)(q / LQ), j = (int)(q % LQ);
  float x = bias[((long)j * LQ + i) * DBI + lane];       // transposed read
  float mu = wred_sum(x) * (1.f / 64.f);
  float ms = wred_sum(x * x) * (1.f / 64.f);
  float r = rsqrtf(ms - mu * mu + 1e-5f);
  float y = (x - mu) * r * g[lane] + b[lane];
  #pragma unroll
  for (int h = 0; h < 4; ++h) {
    float v = y * Wb[lane * 4 + h];
    #pragma unroll
    for (int o = 32; o; o >>= 1) v += __shfl_down(v, o);
    if (lane == 0) logits[((long)h * LQ + i) * LQ + j] = v;
  }
}

// ---------------- kernel 3: projections GEMM + rope/sigmoid epilogue
// grid (16 n-tiles, 1152 m-tiles); n-tile = one (which,h) 48-col chunk
__global__ __launch_bounds__(256) void k_proj(
    const u16* __restrict__ e_ln, const u16* __restrict__ WT,
    const int* __restrict__ edge_pos, const float* __restrict__ bg,
    u16* __restrict__ q_buf, u16* __restrict__ k_buf,
    u16* __restrict__ vT, u16* __restrict__ gate)
{
  __shared__ u16 sA[128 * LDSS];
  __shared__ u16 sB[48 * LDSS];
  __shared__ float sC[128 * 49];
  int nt = blockIdx.x;
  long mt = blockIdx.y;
  int which = nt >> 2, h = nt & 3;
  f32x4 acc[2][3] = {};
  gemm_loop<3>(e_ln + mt * 128 * DE, DE, WT + (long)nt * 48 * DE, DE, 2, sA, sB, acc);
  const int t = threadIdx.x;
  const int w = t >> 6, lane = t & 63, quad = lane >> 4, l16 = lane & 15;
  #pragma unroll
  for (int rf = 0; rf < 2; ++rf)
    #pragma unroll
    for (int f = 0; f < 3; ++f)
      #pragma unroll
      for (int r = 0; r < 4; ++r)
        sC[(w * 32 + rf * 16 + quad * 4 + r) * 49 + f * 16 + l16] = acc[rf][f][r];
  __syncthreads();
  long pbase = mt * 128;
  int n = (int)(pbase / LQ);
  int i2base = (int)(pbase % LQ);   // tiles never cross n (384 = 3*128)
  if (which < 2) {
    // q or k: RoPE (angle indexed by i2, pairs (d, d+24)), then scale
    float scl = (which == 0) ? 0.14433756729740643f : (1.0f / 384.0f);
    u16* dst = (which == 0) ? q_buf : k_buf;
    int row = t >> 1, half = t & 1;
    int i2 = i2base + row;
    float posf = (float)edge_pos[i2];
    long base = ((long)(h * LQ + i2) * LQ + n) * DH;
    #pragma unroll
    for (int kd = 0; kd < 24; kd += 2) {
      u16 y2[2];
      #pragma unroll
      for (int u = 0; u < 2; ++u) {
        int d = half * 24 + kd + u;
        int dd = (d < 24) ? d : d - 24;
        float ang = posf * exp2f((float)dd * (-13.287712379549449f / 24.f));
        float sn = sinf(ang), cs = cosf(ang);
        float x1 = sC[row * 49 + dd], x2 = sC[row * 49 + dd + 24];
        float y = (d < 24) ? (x1 * cs - x2 * sn) : (x1 * sn + x2 * cs);
        y2[u] = f2b(y * scl);
      }
      *(u32*)(dst + base + half * 24 + kd) = (u32)y2[0] | ((u32)y2[1] << 16);
    }
  } else if (which == 2) {
    // v transposed: vT[h][n*48+d][j]; rows of this tile are j
    for (int e = t; e < 6144; e += 256) {
      int d = e >> 7, row = e & 127;
      vT[((long)h * KQK + n * DH + d) * LQ + (i2base + row)] = f2b(sC[row * 49 + d]);
    }
  } else {
    // gate: sigmoid(x + bg) -> gate[p][h*48+d]
    for (int e = t; e < 6144; e += 256) {
      int row = e / 48, d = e - row * 48;
      float xx = sC[row * 49 + d] + bg[h * DH + d];
      gate[(pbase + row) * 192 + h * DH + d] = f2b(1.f / (1.f + expf(-xx)));
    }
  }
}

// ---------------- kernel 4: logits += Q K^T (split-K=8, atomicAdd fp32)
// grid x = splitK*8 + ntile(8), y = mtile(3), z = head(4)
__global__ __launch_bounds__(256) void k_qk(
    const u16* __restrict__ q_buf, const u16* __restrict__ k_buf,
    float* __restrict__ logits)
{
  __shared__ u16 sA[128 * LDSS];
  __shared__ u16 sB[48 * LDSS];
  int nt = blockIdx.x & 7, s = blockIdx.x >> 3;
  int mt = blockIdx.y, h = blockIdx.z;
  f32x4 acc[2][3] = {};
  gemm_loop<3>(q_buf + ((long)h * LQ + mt * 128) * KQK + s * 2304, KQK,
               k_buf + ((long)h * LQ + nt * 48) * KQK + s * 2304, KQK,
               36, sA, sB, acc);
  const int t = threadIdx.x;
  const int w = t >> 6, lane = t & 63, quad = lane >> 4, l16 = lane & 15;
  #pragma unroll
  for (int rf = 0; rf < 2; ++rf)
    #pragma unroll
    for (int f = 0; f < 3; ++f)
      #pragma unroll
      for (int r = 0; r < 4; ++r) {
        int row = mt * 128 + w * 32 + rf * 16 + quad * 4 + r;
        int col = nt * 48 + f * 16 + l16;
        atomicAdd(logits + ((long)h * LQ + row) * LQ + col, acc[rf][f][r]);
      }
}

// ---------------- kernel 5: softmax over j + post-softmax mask -> attn bf16
__global__ __launch_bounds__(256) void k_softmax(
    const float* __restrict__ logits, const float* __restrict__ mask,
    u16* __restrict__ attn)
{
  int w = threadIdx.x >> 6, lane = threadIdx.x & 63;
  long row = (long)blockIdx.x * 4 + w;   // row = h*384 + i
  int i = (int)(row % LQ);
  const float* src = logits + row * LQ;
  float v[6];
  float mx = -1e30f;
  #pragma unroll
  for (int j0 = 0; j0 < 6; ++j0) { v[j0] = src[lane + j0 * 64]; mx = fmaxf(mx, v[j0]); }
  #pragma unroll
  for (int o = 32; o; o >>= 1) mx = fmaxf(mx, __shfl_down(mx, o));
  mx = __shfl(mx, 0);
  float s = 0.f;
  #pragma unroll
  for (int j0 = 0; j0 < 6; ++j0) { v[j0] = expf(v[j0] - mx); s += v[j0]; }
  s = wred_sum(s);
  float inv = 1.f / s;
  #pragma unroll
  for (int j0 = 0; j0 < 6; ++j0) {
    int j = lane + j0 * 64;
    float p = v[j0] * inv + 1.0e6f * (mask[(long)i * LQ + j] - 1.f);
    attn[row * LQ + j] = f2b(p);
  }
}

// ---------------- kernel 6: out_pre = attn @ vT^T  -> out_buf[(n*384+i)*192 + h*48+d]
// grid (384 n-tiles == n, 3 m-tiles, 4 heads)
__global__ __launch_bounds__(256) void k_av(
    const u16* __restrict__ attn, const u16* __restrict__ vT,
    u16* __restrict__ out_buf)
{
  __shared__ u16 sA[128 * LDSS];
  __shared__ u16 sB[48 * LDSS];
  int nt = blockIdx.x, mt = blockIdx.y, h = blockIdx.z;
  f32x4 acc[2][3] = {};
  gemm_loop<3>(attn + ((long)h * LQ + mt * 128) * LQ, LQ,
               vT + ((long)h * KQK + nt * DH) * LQ, LQ,
               6, sA, sB, acc);
  const int t = threadIdx.x;
  const int w = t >> 6, lane = t & 63, quad = lane >> 4, l16 = lane & 15;
  #pragma unroll
  for (int rf = 0; rf < 2; ++rf)
    #pragma unroll
    for (int f = 0; f < 3; ++f)
      #pragma unroll
      for (int r = 0; r < 4; ++r) {
        int i = mt * 128 + w * 32 + rf * 16 + quad * 4 + r;
        int d = f * 16 + l16;
        out_buf[((long)nt * LQ + i) * 192 + h * DH + d] = f2b(acc[rf][f][r]);
      }
}

// ---------------- kernel 7: final = (out .* gate) @ Wo, transposed store
__global__ __launch_bounds__(256) void k_out(
    const u16* __restrict__ out_buf, const u16* __restrict__ gate,
    const u16* __restrict__ WoT, float* __restrict__ outp)
{
  __shared__ u16 sA[128 * LDSS];
  __shared__ u16 sB[64 * LDSS];
  int nt = blockIdx.x;
  long mt = blockIdx.y;
  f32x4 acc[2][4] = {};
  gemm_loop_mul(out_buf + mt * 128 * 192, gate + mt * 128 * 192, 192,
                WoT + (long)nt * 64 * 192, 192, 3, sA, sB, acc);
  const int t = threadIdx.x;
  const int w = t >> 6, lane = t & 63, quad = lane >> 4, l16 = lane & 15;
  long pbase = mt * 128;
  int n = (int)(pbase / LQ), ibase = (int)(pbase % LQ);
  #pragma unroll
  for (int rf = 0; rf < 2; ++rf)
    #pragma unroll
    for (int f = 0; f < 4; ++f)
      #pragma unroll
      for (int r = 0; r < 4; ++r) {
        int row = w * 32 + rf * 16 + quad * 4 + r;
        int c = nt * 64 + f * 16 + l16;
        outp[((long)(ibase + row) * LQ + n) * DE + c] = acc[rf][f][r];
      }
}

extern "C" void kernel_launch(void* const* d_in, const int* in_sizes, int n_in,
                              void* d_out, int out_size, void* d_ws, size_t ws_size,
                              hipStream_t stream)
{
  const float* edge   = (const float*)d_in[0];
  const float* bias   = (const float*)d_in[1];
  const int*   epos   = (const int*)d_in[2];
  const float* mask   = (const float*)d_in[3];
  const float* ln_e_g = (const float*)d_in[4];
  const float* ln_e_b = (const float*)d_in[5];
  const float* ln_b_g = (const float*)d_in[6];
  const float* ln_b_b = (const float*)d_in[7];
  const float* Wq = (const float*)d_in[8];
  const float* Wk = (const float*)d_in[9];
  const float* Wv = (const float*)d_in[10];
  const float* Wb = (const float*)d_in[11];
  const float* Wg = (const float*)d_in[12];
  const float* bg = (const float*)d_in[13];
  const float* Wo = (const float*)d_in[14];
  float* outp = (float*)d_out;

  char* ws = (char*)d_ws;
  const size_t SZ = (size_t)NPOS * 192 * 2;   // 56,623,104 B
  u16* e_ln    = (u16*)ws;                    // [147456][128] bf16 (aliased w/ out_buf)
  u16* out_buf = (u16*)ws;                    // [147456][192] bf16 (after e_ln dead)
  u16* q_buf   = (u16*)(ws + SZ);             // [4][384][18432]
  u16* k_buf   = (u16*)(ws + 2 * SZ);
  u16* vTb     = (u16*)(ws + 3 * SZ);
  u16* gateb   = (u16*)(ws + 4 * SZ);
  float* logits= (float*)(ws + 5 * SZ);       // [4][384][384] fp32
  u16* attn    = (u16*)(ws + 5 * SZ + 2359296);
  u16* WT      = (u16*)(ws + 5 * SZ + 2359296 + 1179648);
  u16* WoT     = (u16*)(ws + 5 * SZ + 2359296 + 1179648 + 196608);

  k_prep_w<<<dim3(384), dim3(256), 0, stream>>>(Wq, Wk, Wv, Wg, Wo, WT, WoT);
  k_ln_e<<<dim3(36864), dim3(256), 0, stream>>>(edge, ln_e_g, ln_e_b, e_ln);
  k_bias<<<dim3(36864), dim3(256), 0, stream>>>(bias, ln_b_g, ln_b_b, Wb, logits);
  k_proj<<<dim3(16, 1152), dim3(256), 0, stream>>>(e_ln, WT, epos, bg, q_buf, k_buf, vTb, gateb);
  k_qk<<<dim3(64, 3, 4), dim3(256), 0, stream>>>(q_buf, k_buf, logits);
  k_softmax<<<dim3(384), dim3(256), 0, stream>>>(logits, mask, attn);
  k_av<<<dim3(384, 3, 4), dim3(256), 0, stream>>>(attn, vTb, out_buf);
  k_out<<<dim3(2, 1152), dim3(256), 0, stream>>>(out_buf, gateb, WoT, outp);
}

// Round 2
// 579.064 us; speedup vs baseline: 1.1826x; 1.1826x over previous
//
#include <hip/hip_runtime.h>
#include <hip/hip_bf16.h>

// BiasedAxialAttention MI355X round 2: A-resident k_proj + RoPE tables,
// wide 128x192 tiles for QK/AV, 128x128 for out-proj.

#define LQ 384
#define DE 128
#define DBI 64
#define DH 48
#define NPOS (LQ*LQ)     // 147456
#define KQK (LQ*DH)      // 18432

typedef __attribute__((ext_vector_type(8))) short short8;
typedef __attribute__((ext_vector_type(4))) float f32x4;
typedef unsigned short u16;
typedef unsigned int u32;

__device__ __forceinline__ float b2f(u16 u) {
  union { u32 i; float f; } v; v.i = ((u32)u) << 16; return v.f;
}
__device__ __forceinline__ u16 f2b(float f) {
  __hip_bfloat16 h = __float2bfloat16(f);
  return __builtin_bit_cast(unsigned short, h);
}
__device__ __forceinline__ float wred_sum(float v) {
  #pragma unroll
  for (int o = 32; o; o >>= 1) v += __shfl_down(v, o);
  return __shfl(v, 0);
}

// ---------------- 128x192 NT-GEMM mainloop, BK=64, 4 waves as 2x2 (wave=64x96)
__device__ __forceinline__ void gemm_128x192(
    const u16* __restrict__ A, long lda, const u16* __restrict__ B, long ldb,
    int kTiles, u16* sA, u16* sB, f32x4 (&acc)[4][6])
{
  const int t = threadIdx.x;
  const int w = t >> 6, lane = t & 63, quad = lane >> 4, l16 = lane & 15;
  const int wr = w >> 1, wc = w & 1;
  for (int kt = 0; kt < kTiles; ++kt) {
    #pragma unroll
    for (int r = 0; r < 4; ++r) {
      int id = t + r * 256, row = id >> 3, c8 = (id & 7) * 8;
      *(uint4*)(sA + row * 72 + c8) = *(const uint4*)(A + (long)row * lda + kt * 64 + c8);
    }
    #pragma unroll
    for (int r = 0; r < 6; ++r) {
      int id = t + r * 256, row = id >> 3, c8 = (id & 7) * 8;
      *(uint4*)(sB + row * 72 + c8) = *(const uint4*)(B + (long)row * ldb + kt * 64 + c8);
    }
    __syncthreads();
    #pragma unroll
    for (int kk = 0; kk < 64; kk += 32) {
      short8 a[4], bf[6];
      #pragma unroll
      for (int rr = 0; rr < 4; ++rr)
        a[rr] = *(const short8*)(sA + (wr * 64 + rr * 16 + l16) * 72 + kk + quad * 8);
      #pragma unroll
      for (int f = 0; f < 6; ++f)
        bf[f] = *(const short8*)(sB + (wc * 96 + f * 16 + l16) * 72 + kk + quad * 8);
      #pragma unroll
      for (int rr = 0; rr < 4; ++rr)
        #pragma unroll
        for (int f = 0; f < 6; ++f)
          acc[rr][f] = __builtin_amdgcn_mfma_f32_16x16x32_bf16(a[rr], bf[f], acc[rr][f], 0, 0, 0);
    }
    __syncthreads();
  }
}

// ---------------- kernel 0: weight transposes + RoPE tables
__global__ __launch_bounds__(256) void k_prep_w(
    const float* __restrict__ Wq, const float* __restrict__ Wk,
    const float* __restrict__ Wv, const float* __restrict__ Wg,
    const float* __restrict__ Wo, const int* __restrict__ epos,
    u16* __restrict__ WT, u16* __restrict__ WoT,
    float* __restrict__ cosT, float* __restrict__ sinT)
{
  int idx = blockIdx.x * 256 + threadIdx.x;
  if (idx < 768 * 128) {
    int col = idx >> 7, c = idx & 127;
    int which = col / 192, wi = col % 192;
    const float* W = (which == 0) ? Wq : (which == 1) ? Wk : (which == 2) ? Wv : Wg;
    WT[(long)col * 128 + c] = f2b(W[(long)c * 192 + wi]);
  }
  if (idx < 128 * 192) {
    int c = idx / 192, col = idx % 192;
    WoT[(long)c * 192 + col] = f2b(Wo[(long)col * 128 + c]);
  }
  if (idx < 384 * 24) {
    int i2 = idx / 24, dd = idx % 24;
    float ang = (float)epos[i2] * exp2f((float)dd * (-13.287712379549449f / 24.f));
    cosT[idx] = cosf(ang);
    sinT[idx] = sinf(ang);
  }
}

// ---------------- kernel 1: LN of transposed edge -> e_ln bf16 [p=n*384+i][128]
__global__ __launch_bounds__(256) void k_ln_e(
    const float* __restrict__ edge, const float* __restrict__ g,
    const float* __restrict__ b, u16* __restrict__ e_ln)
{
  int w = threadIdx.x >> 6, lane = threadIdx.x & 63;
  long p = (long)blockIdx.x * 4 + w;
  int n = (int)(p / LQ), i2 = (int)(p % LQ);
  const float* src = edge + ((long)i2 * LQ + n) * DE;   // transposed read
  float2 x = *(const float2*)(src + lane * 2);
  float mu = wred_sum(x.x + x.y) * (1.f / 128.f);
  float ms = wred_sum(x.x * x.x + x.y * x.y) * (1.f / 128.f);
  float r = rsqrtf(ms - mu * mu + 1e-5f);
  int c = lane * 2;
  u16 y0 = f2b((x.x - mu) * r * g[c] + b[c]);
  u16 y1 = f2b((x.y - mu) * r * g[c + 1] + b[c + 1]);
  *(u32*)(e_ln + p * DE + c) = (u32)y0 | ((u32)y1 << 16);
}

// ---------------- kernel 2: LN(bias^T) @ Wb -> logits init (= b_h) [h][i][j]
__global__ __launch_bounds__(256) void k_bias(
    const float* __restrict__ bias, const float* __restrict__ g,
    const float* __restrict__ b, const float* __restrict__ Wb,
    float* __restrict__ logits)
{
  int w = threadIdx.x >> 6, lane = threadIdx.x & 63;
  long q = (long)blockIdx.x * 4 + w;
  int i = (int)(q / LQ), j = (int)(q % LQ);
  float x = bias[((long)j * LQ + i) * DBI + lane];       // transposed read
  float mu = wred_sum(x) * (1.f / 64.f);
  float ms = wred_sum(x * x) * (1.f / 64.f);
  float r = rsqrtf(ms - mu * mu + 1e-5f);
  float y = (x - mu) * r * g[lane] + b[lane];
  #pragma unroll
  for (int h = 0; h < 4; ++h) {
    float v = y * Wb[lane * 4 + h];
    #pragma unroll
    for (int o = 32; o; o >>= 1) v += __shfl_down(v, o);
    if (lane == 0) logits[((long)h * LQ + i) * LQ + j] = v;
  }
}

// ---------------- kernel 3: projections, A-resident. grid (1152)
// Block: stage e_ln tile [128x128] once, loop 16 chunks of 48 cols.
__global__ __launch_bounds__(256) void k_proj(
    const u16* __restrict__ e_ln, const u16* __restrict__ WT,
    const float* __restrict__ cosT, const float* __restrict__ sinT,
    const float* __restrict__ bg,
    u16* __restrict__ q_buf, u16* __restrict__ k_buf,
    u16* __restrict__ vT, u16* __restrict__ gate)
{
  __shared__ __align__(16) u16 sA[128 * 136];       // 34816 B
  __shared__ __align__(16) char sU[128 * 49 * 4];   // 25088 B (sB/sC union)
  const int t = threadIdx.x;
  const int w = t >> 6, lane = t & 63, quad = lane >> 4, l16 = lane & 15;
  long mt = blockIdx.x;
  long pbase = mt * 128;
  int n = (int)(pbase / LQ), i2base = (int)(pbase % LQ);

  // stage A once: 128 rows x 128 K
  #pragma unroll
  for (int r = 0; r < 8; ++r) {
    int id = t + r * 256, row = id >> 4, c8 = (id & 15) * 8;
    *(uint4*)(sA + row * 136 + c8) = *(const uint4*)(e_ln + (pbase + row) * DE + c8);
  }
  __syncthreads();
  short8 a[2][4];
  #pragma unroll
  for (int rr = 0; rr < 2; ++rr)
    #pragma unroll
    for (int kki = 0; kki < 4; ++kki)
      a[rr][kki] = *(const short8*)(sA + (w * 32 + rr * 16 + l16) * 136 + kki * 32 + quad * 8);

  for (int cc = 0; cc < 16; ++cc) {
    int which = cc >> 2, h = cc & 3;
    u16* sB = (u16*)sU;
    #pragma unroll
    for (int r = 0; r < 3; ++r) {
      int id = t + r * 256, row = id >> 4, c8 = (id & 15) * 8;
      *(uint4*)(sB + row * 136 + c8) = *(const uint4*)(WT + ((long)cc * 48 + row) * DE + c8);
    }
    __syncthreads();
    f32x4 acc[2][3] = {};
    #pragma unroll
    for (int kki = 0; kki < 4; ++kki)
      #pragma unroll
      for (int f = 0; f < 3; ++f) {
        short8 bf = *(const short8*)(sB + (f * 16 + l16) * 136 + kki * 32 + quad * 8);
        acc[0][f] = __builtin_amdgcn_mfma_f32_16x16x32_bf16(a[0][kki], bf, acc[0][f], 0, 0, 0);
        acc[1][f] = __builtin_amdgcn_mfma_f32_16x16x32_bf16(a[1][kki], bf, acc[1][f], 0, 0, 0);
      }
    __syncthreads();
    float* sC = (float*)sU;
    #pragma unroll
    for (int rr = 0; rr < 2; ++rr)
      #pragma unroll
      for (int f = 0; f < 3; ++f)
        #pragma unroll
        for (int r = 0; r < 4; ++r)
          sC[(w * 32 + rr * 16 + quad * 4 + r) * 49 + f * 16 + l16] = acc[rr][f][r];
    __syncthreads();
    if (which < 2) {
      float scl = (which == 0) ? 0.14433756729740643f : (1.0f / 384.0f);
      u16* dst = (which == 0) ? q_buf : k_buf;
      int row = t >> 1, half = t & 1;
      int i2 = i2base + row;
      const float* ct = cosT + i2 * 24;
      const float* st = sinT + i2 * 24;
      long base = ((long)(h * LQ + i2) * LQ + n) * DH;
      #pragma unroll
      for (int kd = 0; kd < 24; kd += 2) {
        u16 y2[2];
        #pragma unroll
        for (int u = 0; u < 2; ++u) {
          int d = half * 24 + kd + u;
          int dd = (d < 24) ? d : d - 24;
          float cs = ct[dd], sn = st[dd];
          float x1 = sC[row * 49 + dd], x2 = sC[row * 49 + dd + 24];
          float y = (d < 24) ? (x1 * cs - x2 * sn) : (x1 * sn + x2 * cs);
          y2[u] = f2b(y * scl);
        }
        *(u32*)(dst + base + half * 24 + kd) = (u32)y2[0] | ((u32)y2[1] << 16);
      }
    } else if (which == 2) {
      for (int e = t; e < 6144; e += 256) {
        int d = e >> 7, row = e & 127;
        vT[((long)h * KQK + n * DH + d) * LQ + (i2base + row)] = f2b(sC[row * 49 + d]);
      }
    } else {
      for (int e = t; e < 6144; e += 256) {
        int row = e / 48, d = e - row * 48;
        float xx = sC[row * 49 + d] + bg[h * DH + d];
        gate[(pbase + row) * 192 + h * DH + d] = f2b(1.f / (1.f + expf(-xx)));
      }
    }
    __syncthreads();
  }
}

// ---------------- kernel 4: logits += Q K^T. grid x = s*2+nt (64), y=mt(3), z=h(4)
__global__ __launch_bounds__(256) void k_qk(
    const u16* __restrict__ q_buf, const u16* __restrict__ k_buf,
    float* __restrict__ logits)
{
  __shared__ __align__(16) u16 sA[128 * 72];
  __shared__ __align__(16) u16 sB[192 * 72];
  int nt = blockIdx.x & 1, s = blockIdx.x >> 1;
  int mt = blockIdx.y, h = blockIdx.z;
  f32x4 acc[4][6] = {};
  gemm_128x192(q_buf + ((long)h * LQ + mt * 128) * KQK + s * 576, KQK,
               k_buf + ((long)h * LQ + nt * 192) * KQK + s * 576, KQK,
               9, sA, sB, acc);
  const int t = threadIdx.x;
  const int w = t >> 6, lane = t & 63, quad = lane >> 4, l16 = lane & 15;
  const int wr = w >> 1, wc = w & 1;
  #pragma unroll
  for (int rr = 0; rr < 4; ++rr)
    #pragma unroll
    for (int f = 0; f < 6; ++f)
      #pragma unroll
      for (int r = 0; r < 4; ++r) {
        int row = mt * 128 + wr * 64 + rr * 16 + quad * 4 + r;
        int col = nt * 192 + wc * 96 + f * 16 + l16;
        atomicAdd(logits + ((long)h * LQ + row) * LQ + col, acc[rr][f][r]);
      }
}

// ---------------- kernel 5: softmax over j + post-softmax mask -> attn bf16
__global__ __launch_bounds__(256) void k_softmax(
    const float* __restrict__ logits, const float* __restrict__ mask,
    u16* __restrict__ attn)
{
  int w = threadIdx.x >> 6, lane = threadIdx.x & 63;
  long row = (long)blockIdx.x * 4 + w;   // row = h*384 + i
  int i = (int)(row % LQ);
  const float* src = logits + row * LQ;
  float v[6];
  float mx = -1e30f;
  #pragma unroll
  for (int j0 = 0; j0 < 6; ++j0) { v[j0] = src[lane + j0 * 64]; mx = fmaxf(mx, v[j0]); }
  #pragma unroll
  for (int o = 32; o; o >>= 1) mx = fmaxf(mx, __shfl_down(mx, o));
  mx = __shfl(mx, 0);
  float s = 0.f;
  #pragma unroll
  for (int j0 = 0; j0 < 6; ++j0) { v[j0] = expf(v[j0] - mx); s += v[j0]; }
  s = wred_sum(s);
  float inv = 1.f / s;
  #pragma unroll
  for (int j0 = 0; j0 < 6; ++j0) {
    int j = lane + j0 * 64;
    float p = v[j0] * inv + 1.0e6f * (mask[(long)i * LQ + j] - 1.f);
    attn[row * LQ + j] = f2b(p);
  }
}

// ---------------- kernel 6: out = attn @ vT^T. grid (96, 3, 4)
__global__ __launch_bounds__(256) void k_av(
    const u16* __restrict__ attn, const u16* __restrict__ vT,
    u16* __restrict__ out_buf)
{
  __shared__ __align__(16) u16 sA[128 * 72];
  __shared__ __align__(16) u16 sB[192 * 72];
  int nt = blockIdx.x, mt = blockIdx.y, h = blockIdx.z;
  f32x4 acc[4][6] = {};
  gemm_128x192(attn + ((long)h * LQ + mt * 128) * LQ, LQ,
               vT + ((long)h * KQK + nt * 192) * LQ, LQ,
               6, sA, sB, acc);
  const int t = threadIdx.x;
  const int w = t >> 6, lane = t & 63, quad = lane >> 4, l16 = lane & 15;
  const int wr = w >> 1, wc = w & 1;
  #pragma unroll
  for (int rr = 0; rr < 4; ++rr)
    #pragma unroll
    for (int f = 0; f < 6; ++f)
      #pragma unroll
      for (int r = 0; r < 4; ++r) {
        int i = mt * 128 + wr * 64 + rr * 16 + quad * 4 + r;
        int C = nt * 192 + wc * 96 + f * 16 + l16;
        int nn = C / 48, d = C - nn * 48;
        out_buf[((long)nn * LQ + i) * 192 + h * DH + d] = f2b(acc[rr][f][r]);
      }
}

// ---------------- kernel 7: final = (out .* gate) @ Wo, 128x128 tile. grid (1152)
__global__ __launch_bounds__(256) void k_out(
    const u16* __restrict__ out_buf, const u16* __restrict__ gate,
    const u16* __restrict__ WoT, float* __restrict__ outp)
{
  __shared__ __align__(16) u16 sA[128 * 72];
  __shared__ __align__(16) u16 sB[128 * 72];
  long mt = blockIdx.x;
  const int t = threadIdx.x;
  const int w = t >> 6, lane = t & 63, quad = lane >> 4, l16 = lane & 15;
  const int wr = w >> 1, wc = w & 1;
  f32x4 acc[4][4] = {};
  const u16* A1 = out_buf + mt * 128 * 192;
  const u16* A2 = gate + mt * 128 * 192;
  for (int kt = 0; kt < 3; ++kt) {
    #pragma unroll
    for (int r = 0; r < 4; ++r) {
      int id = t + r * 256, row = id >> 3, c8 = (id & 7) * 8;
      long off = (long)row * 192 + kt * 64 + c8;
      union { u16 s[8]; uint4 v; } ua, ub, ur;
      ua.v = *(const uint4*)(A1 + off);
      ub.v = *(const uint4*)(A2 + off);
      #pragma unroll
      for (int q2 = 0; q2 < 8; ++q2) ur.s[q2] = f2b(b2f(ua.s[q2]) * b2f(ub.s[q2]));
      *(uint4*)(sA + row * 72 + c8) = ur.v;
    }
    #pragma unroll
    for (int r = 0; r < 4; ++r) {
      int id = t + r * 256, row = id >> 3, c8 = (id & 7) * 8;
      *(uint4*)(sB + row * 72 + c8) = *(const uint4*)(WoT + (long)row * 192 + kt * 64 + c8);
    }
    __syncthreads();
    #pragma unroll
    for (int kk = 0; kk < 64; kk += 32) {
      short8 a[4], bf[4];
      #pragma unroll
      for (int rr = 0; rr < 4; ++rr)
        a[rr] = *(const short8*)(sA + (wr * 64 + rr * 16 + l16) * 72 + kk + quad * 8);
      #pragma unroll
      for (int f = 0; f < 4; ++f)
        bf[f] = *(const short8*)(sB + (wc * 64 + f * 16 + l16) * 72 + kk + quad * 8);
      #pragma unroll
      for (int rr = 0; rr < 4; ++rr)
        #pragma unroll
        for (int f = 0; f < 4; ++f)
          acc[rr][f] = __builtin_amdgcn_mfma_f32_16x16x32_bf16(a[rr], bf[f], acc[rr][f], 0, 0, 0);
    }
    __syncthreads();
  }
  long pbase = mt * 128;
  int n = (int)(pbase / LQ), ibase = (int)(pbase % LQ);
  #pragma unroll
  for (int rr = 0; rr < 4; ++rr)
    #pragma unroll
    for (int f = 0; f < 4; ++f)
      #pragma unroll
      for (int r = 0; r < 4; ++r) {
        int row = wr * 64 + rr * 16 + quad * 4 + r;
        int c = wc * 64 + f * 16 + l16;
        outp[((long)(ibase + row) * LQ + n) * DE + c] = acc[rr][f][r];
      }
}

extern "C" void kernel_launch(void* const* d_in, const int* in_sizes, int n_in,
                              void* d_out, int out_size, void* d_ws, size_t ws_size,
                              hipStream_t stream)
{
  const float* edge   = (const float*)d_in[0];
  const float* bias   = (const float*)d_in[1];
  const int*   epos   = (const int*)d_in[2];
  const float* mask   = (const float*)d_in[3];
  const float* ln_e_g = (const float*)d_in[4];
  const float* ln_e_b = (const float*)d_in[5];
  const float* ln_b_g = (const float*)d_in[6];
  const float* ln_b_b = (const float*)d_in[7];
  const float* Wq = (const float*)d_in[8];
  const float* Wk = (const float*)d_in[9];
  const float* Wv = (const float*)d_in[10];
  const float* Wb = (const float*)d_in[11];
  const float* Wg = (const float*)d_in[12];
  const float* bg = (const float*)d_in[13];
  const float* Wo = (const float*)d_in[14];
  float* outp = (float*)d_out;

  char* ws = (char*)d_ws;
  const size_t SZ = (size_t)NPOS * 192 * 2;   // 56,623,104 B
  u16* e_ln    = (u16*)ws;                    // [147456][128] bf16 (aliased w/ out_buf)
  u16* out_buf = (u16*)ws;                    // [147456][192] bf16 (after e_ln dead)
  u16* q_buf   = (u16*)(ws + SZ);             // [4][384][18432]
  u16* k_buf   = (u16*)(ws + 2 * SZ);
  u16* vTb     = (u16*)(ws + 3 * SZ);
  u16* gateb   = (u16*)(ws + 4 * SZ);
  float* logits= (float*)(ws + 5 * SZ);       // [4][384][384] fp32
  u16* attn    = (u16*)(ws + 5 * SZ + 2359296);
  u16* WT      = (u16*)(ws + 5 * SZ + 2359296 + 1179648);
  u16* WoT     = (u16*)(ws + 5 * SZ + 2359296 + 1179648 + 196608);
  float* cosT  = (float*)(ws + 5 * SZ + 2359296 + 1179648 + 196608 + 49152);
  float* sinT  = cosT + 384 * 24;

  k_prep_w<<<dim3(384), dim3(256), 0, stream>>>(Wq, Wk, Wv, Wg, Wo, epos, WT, WoT, cosT, sinT);
  k_ln_e<<<dim3(36864), dim3(256), 0, stream>>>(edge, ln_e_g, ln_e_b, e_ln);
  k_bias<<<dim3(36864), dim3(256), 0, stream>>>(bias, ln_b_g, ln_b_b, Wb, logits);
  k_proj<<<dim3(1152), dim3(256), 0, stream>>>(e_ln, WT, cosT, sinT, bg, q_buf, k_buf, vTb, gateb);
  k_qk<<<dim3(64, 3, 4), dim3(256), 0, stream>>>(q_buf, k_buf, logits);
  k_softmax<<<dim3(384), dim3(256), 0, stream>>>(logits, mask, attn);
  k_av<<<dim3(96, 3, 4), dim3(256), 0, stream>>>(attn, vTb, out_buf);
  k_out<<<dim3(1152), dim3(256), 0, stream>>>(out_buf, gateb, WoT, outp);
}